// Round 6
// baseline (216.339 us; speedup 1.0000x reference)
//
#include <hip/hip_runtime.h>

typedef float f32x4 __attribute__((ext_vector_type(4)));
typedef short s16x8 __attribute__((ext_vector_type(8)));
typedef unsigned short us4 __attribute__((ext_vector_type(4)));

#define MFMA16(a, b, c) __builtin_amdgcn_mfma_f32_16x16x32_bf16(a, b, c, 0, 0, 0)

// async global->LDS DMA, 16B per lane. LDS dest must be wave-uniform base + lane*16.
#define GLOAD_LDS16(gp, lp) __builtin_amdgcn_global_load_lds( \
    (__attribute__((address_space(1))) void*)(gp),            \
    (__attribute__((address_space(3))) void*)(lp), 16, 0, 0)

__device__ __forceinline__ unsigned short f2bf(float f) {
    union { float f; unsigned u; } v; v.f = f;
    unsigned r = v.u + 0x7fffu + ((v.u >> 16) & 1u);   // RNE truncate to bf16
    return (unsigned short)(r >> 16);
}

// ---------------------------------------------------------------------------
// BK=64 GEMM core, 128x128 tile: C += A[128xK] @ B[128xK]^T, both row-major.
// LDS tiles 128x64 bf16 (16 KB each) with XOR swizzle: 16B-chunk at logical
// (row, ch) is stored at (row, ch ^ (row&7)). Staging dest stays lane-linear
// (global_load_lds constraint); swizzle applied to the SOURCE chunk index.
// Fragment reads then hit all 32 banks (2-way alias = free).
// Per iter: 8 GLOADs in flight per drain, 16 ds_read_b128, 32 MFMA.
// ---------------------------------------------------------------------------
__device__ __forceinline__ void gemm_core128_bk64(
    const unsigned short* __restrict__ Ab, size_t Astride,
    const unsigned short* __restrict__ Bb, size_t Bstride,
    int K, unsigned short* As, unsigned short* Bs,
    int t, f32x4 acc[4][4])
{
    const int wave = t >> 6, lane = t & 63;
    const int c = lane & 15, quad = lane >> 4;
    const int wm = (wave >> 1) * 64, wn = (wave & 1) * 64;

    for (int k0 = 0; k0 < K; k0 += 64) {
        __syncthreads();
        #pragma unroll
        for (int i = 0; i < 4; i++) {
            int idx = i * 256 + t;
            int row = idx >> 3;
            int sch = (idx & 7) ^ (row & 7);          // source chunk for this slot
            GLOAD_LDS16(Ab + (size_t)row * Astride + k0 + sch * 8, As + idx * 8);
            GLOAD_LDS16(Bb + (size_t)row * Bstride + k0 + sch * 8, Bs + idx * 8);
        }
        __syncthreads();

        #pragma unroll
        for (int s = 0; s < 2; s++) {
            s16x8 af[4], bfr[4];
            #pragma unroll
            for (int i = 0; i < 4; i++) {
                int r = wm + i * 16 + c;
                af[i] = *(const s16x8*)(As + r * 64 + (((s << 2) | quad) ^ (r & 7)) * 8);
            }
            #pragma unroll
            for (int i = 0; i < 4; i++) {
                int r = wn + i * 16 + c;
                bfr[i] = *(const s16x8*)(Bs + r * 64 + (((s << 2) | quad) ^ (r & 7)) * 8);
            }
            #pragma unroll
            for (int mt = 0; mt < 4; mt++)
                #pragma unroll
                for (int nt = 0; nt < 4; nt++)
                    acc[mt][nt] = MFMA16(af[mt], bfr[nt], acc[mt][nt]);
        }
    }
}

// ---------------------------------------------------------------------------
// Kernel 1: convert x -> bf16 row-major; W{q,k,v} -> bf16 transposed [n][k];
// zero the l accumulator.
// ---------------------------------------------------------------------------
__global__ __launch_bounds__(256) void k_convert(
    const float* __restrict__ x, const float* __restrict__ wq,
    const float* __restrict__ wk, const float* __restrict__ wv,
    unsigned short* __restrict__ xbf, unsigned short* __restrict__ wt,
    float* __restrict__ lg)
{
    int bid = blockIdx.x, t = threadIdx.x;
    if (bid < 4096) {
        int gid = bid * 256 + t;
        float4 v = ((const float4*)x)[gid];
        us4 o = { f2bf(v.x), f2bf(v.y), f2bf(v.z), f2bf(v.w) };
        ((us4*)xbf)[gid] = o;
    } else if (bid < 7168) {
        int idx = (bid - 4096) * 256 + t;
        int w = idx >> 18;
        int r = idx & 262143;
        int k = r >> 9, n = r & 511;
        const float* src = (w == 0) ? wq : (w == 1) ? wk : wv;
        wt[((size_t)(w * 512 + n) << 9) + k] = f2bf(src[r]);
    } else {
        lg[(bid - 7168) * 256 + t] = 0.f;
    }
}

// ---------------------------------------------------------------------------
// prior body: one block per (b,i) row. sigma = x_row.Ws; row-normalized
// gaussian (inv_norm prefactor cancels). float4 stores.
// ---------------------------------------------------------------------------
__device__ __forceinline__ void prior_body(
    const float* __restrict__ x, const float* __restrict__ wsv,
    float* __restrict__ pout, int blk, int t, float* red, float* red2)
{
    int i = blk & 2047;
    const float* xr = x + (size_t)blk * 512;

    float part = xr[t] * wsv[t] + xr[t + 256] * wsv[t + 256];
    #pragma unroll
    for (int o = 32; o; o >>= 1) part += __shfl_xor(part, o, 64);
    if ((t & 63) == 0) red[t >> 6] = part;
    __syncthreads();
    float sigma = red[0] + red[1] + red[2] + red[3];

    float inv2 = 0.5f / (sigma * sigma);
    float g[8];
    float sum = 0.f;
    int j0 = t * 8;
    #pragma unroll
    for (int u = 0; u < 8; u++) {
        int j = j0 + u;
        float d = (float)(j - i);
        g[u] = (j == i) ? 1.0f : __expf(-(d * d) * inv2);
        sum += g[u];
    }
    #pragma unroll
    for (int o = 32; o; o >>= 1) sum += __shfl_xor(sum, o, 64);
    if ((t & 63) == 0) red2[t >> 6] = sum;
    __syncthreads();
    float inv = 1.0f / (red2[0] + red2[1] + red2[2] + red2[3]);

    float* pr = pout + (size_t)blk * 2048 + j0;
    float4 o0 = { g[0] * inv, g[1] * inv, g[2] * inv, g[3] * inv };
    float4 o1 = { g[4] * inv, g[5] * inv, g[6] * inv, g[7] * inv };
    ((float4*)pr)[0] = o0;
    ((float4*)pr)[1] = o1;
}

// ---------------------------------------------------------------------------
// Kernel 2: QKV projection (+ optional merged prior blocks).
// 1D grid: bid < 768 -> proj tile (bx = bid&63, by = bid>>6);
//          bid >= 768 -> prior row (bid-768)  [ws path only].
// by in [0,8): Q/K swapped roles (A=W outdims, B=x tokens) -> us4 stores.
// by in [8,12): V, original roles -> transposed vtbf [b][d][n], us4 stores.
// ---------------------------------------------------------------------------
__global__ __launch_bounds__(256) void k_proj(
    const unsigned short* __restrict__ xbf, const unsigned short* __restrict__ wt,
    unsigned short* __restrict__ qbf, unsigned short* __restrict__ kbf,
    unsigned short* __restrict__ vtbf,
    const float* __restrict__ x, const float* __restrict__ wsv,
    float* __restrict__ pout)
{
    __shared__ __align__(16) unsigned short As[128 * 64];
    __shared__ __align__(16) unsigned short Bs[128 * 64];
    __shared__ float red[4];
    __shared__ float red2[4];

    int bid = blockIdx.x, t = threadIdx.x;
    if (bid >= 768) {
        prior_body(x, wsv, pout, bid - 768, t, red, red2);
        return;
    }

    int bx = bid & 63, by = bid >> 6;
    int wave = t >> 6, lane = t & 63, c = lane & 15, quad = lane >> 4;
    int wm = (wave >> 1) * 64, wn = (wave & 1) * 64;
    f32x4 acc[4][4] = {};

    if (by < 8) {
        int m0 = by * 128;                         // outdim in [0,1024) = [Q|K]
        int tok0 = bx * 128;
        gemm_core128_bk64(wt + (size_t)m0 * 512, 512, xbf + (size_t)tok0 * 512, 512,
                          512, As, Bs, t, acc);

        unsigned short* dst = (m0 < 512) ? qbf : kbf;   // block-uniform
        int mbase = m0 & 511;
        #pragma unroll
        for (int mt = 0; mt < 4; mt++) {
            int dim0 = mbase + wm + mt * 16 + quad * 4;
            #pragma unroll
            for (int nt = 0; nt < 4; nt++) {
                int token = tok0 + wn + nt * 16 + c;
                us4 pk = { f2bf(acc[mt][nt][0]), f2bf(acc[mt][nt][1]),
                           f2bf(acc[mt][nt][2]), f2bf(acc[mt][nt][3]) };
                *(us4*)(dst + (size_t)token * 512 + dim0) = pk;
            }
        }
    } else {
        int m0 = bx * 128;                         // token
        int n0 = 1024 + (by - 8) * 128;            // V outdim rows in wt
        gemm_core128_bk64(xbf + (size_t)m0 * 512, 512, wt + (size_t)n0 * 512, 512,
                          512, As, Bs, t, acc);

        #pragma unroll
        for (int mt = 0; mt < 4; mt++) {
            int rw0 = m0 + wm + mt * 16 + quad * 4;      // 4 consecutive tokens
            int bb = rw0 >> 11, nn = rw0 & 2047;
            #pragma unroll
            for (int nt = 0; nt < 4; nt++) {
                int d = (n0 - 1024) + wn + nt * 16 + c;
                us4 pk = { f2bf(acc[mt][nt][0]), f2bf(acc[mt][nt][1]),
                           f2bf(acc[mt][nt][2]), f2bf(acc[mt][nt][3]) };
                *(us4*)(vtbf + ((size_t)(bb * 512 + d)) * 2048 + nn) = pk;
            }
        }
    }
}

// ---------------------------------------------------------------------------
// Kernel 3: scores, swapped roles (computes S^T tile: A=K keys, B=Q queries).
// Lane holds 4 consecutive keys of one q-row -> us4 stores into row-major
// P[q][key]. l: shfl across quads + one atomicAdd per q per wave-quadrant.
// Grid (16,16,4).
// ---------------------------------------------------------------------------
__global__ __launch_bounds__(256) void k_score(
    const unsigned short* __restrict__ qbf, const unsigned short* __restrict__ kbf,
    unsigned short* __restrict__ pbf, float* __restrict__ lg)
{
    __shared__ __align__(16) unsigned short As[128 * 64];
    __shared__ __align__(16) unsigned short Bs[128 * 64];

    int t = threadIdx.x;
    int b = blockIdx.z;
    int kt0 = blockIdx.x * 128, q0 = blockIdx.y * 128;

    f32x4 acc[4][4] = {};
    gemm_core128_bk64(kbf + (size_t)(b * 2048 + kt0) * 512, 512,
                      qbf + (size_t)(b * 2048 + q0) * 512, 512,
                      512, As, Bs, t, acc);

    int wave = t >> 6, lane = t & 63, c = lane & 15, quad = lane >> 4;
    int wm = (wave >> 1) * 64, wn = (wave & 1) * 64;
    const float scale = 0.044194173824159216f;    // 1/sqrt(512)

    #pragma unroll
    for (int nt = 0; nt < 4; nt++) {
        int q = q0 + wn + nt * 16 + c;
        float rs = 0.f;
        unsigned short* pr = pbf + (size_t)(b * 2048 + q) * 2048 + kt0 + wm + quad * 4;
        #pragma unroll
        for (int mt = 0; mt < 4; mt++) {
            us4 pk;
            #pragma unroll
            for (int r = 0; r < 4; r++) {
                float p = __expf(acc[mt][nt][r] * scale);
                rs += p;
                pk[r] = f2bf(p);
            }
            *(us4*)(pr + mt * 16) = pk;
        }
        rs += __shfl_xor(rs, 16);
        rs += __shfl_xor(rs, 32);
        if (quad == 0) atomicAdd(&lg[b * 2048 + q], rs);
    }
}

// ---------------------------------------------------------------------------
// Kernel 4: output, swapped roles: O^T tile = Vt(A, 64 d-rows) @ P(B, 128
// q-rows)^T, K=2048 in BK=64 (32 iters). Lane holds 4 consecutive d of one
// q-row -> float4 stores into row-major zout. Grid (8,16,4) = 512 blocks.
// ---------------------------------------------------------------------------
__global__ __launch_bounds__(256) void k_out(
    const unsigned short* __restrict__ pbf, const unsigned short* __restrict__ vtbf,
    const float* __restrict__ lg, float* __restrict__ zout)
{
    __shared__ __align__(16) unsigned short As[64 * 64];    // Vt tile (8 KB)
    __shared__ __align__(16) unsigned short Bs[128 * 64];   // P tile (16 KB)
    __shared__ float invl[128];

    int t = threadIdx.x;
    int b = blockIdx.z;
    int d0 = blockIdx.x * 64, q0 = blockIdx.y * 128;

    if (t < 128) invl[t] = 1.0f / lg[b * 2048 + q0 + t];

    const unsigned short* Ab = vtbf + (size_t)(b * 512 + d0) * 2048;
    const unsigned short* Bb = pbf + (size_t)(b * 2048 + q0) * 2048;

    const int wave = t >> 6, lane = t & 63;
    const int c = lane & 15, quad = lane >> 4;
    const int wm = (wave >> 1) * 32, wn = (wave & 1) * 64;

    f32x4 acc[2][4] = {};

    for (int k0 = 0; k0 < 2048; k0 += 64) {
        __syncthreads();
        #pragma unroll
        for (int i = 0; i < 2; i++) {
            int idx = i * 256 + t;
            int row = idx >> 3;
            int sch = (idx & 7) ^ (row & 7);
            GLOAD_LDS16(Ab + (size_t)row * 2048 + k0 + sch * 8, As + idx * 8);
        }
        #pragma unroll
        for (int i = 0; i < 4; i++) {
            int idx = i * 256 + t;
            int row = idx >> 3;
            int sch = (idx & 7) ^ (row & 7);
            GLOAD_LDS16(Bb + (size_t)row * 2048 + k0 + sch * 8, Bs + idx * 8);
        }
        __syncthreads();

        #pragma unroll
        for (int s = 0; s < 2; s++) {
            s16x8 af[2], bfr[4];
            #pragma unroll
            for (int i = 0; i < 2; i++) {
                int r = wm + i * 16 + c;
                af[i] = *(const s16x8*)(As + r * 64 + (((s << 2) | quad) ^ (r & 7)) * 8);
            }
            #pragma unroll
            for (int i = 0; i < 4; i++) {
                int r = wn + i * 16 + c;
                bfr[i] = *(const s16x8*)(Bs + r * 64 + (((s << 2) | quad) ^ (r & 7)) * 8);
            }
            #pragma unroll
            for (int mt = 0; mt < 2; mt++)
                #pragma unroll
                for (int nt = 0; nt < 4; nt++)
                    acc[mt][nt] = MFMA16(af[mt], bfr[nt], acc[mt][nt]);
        }
    }

    #pragma unroll
    for (int mt = 0; mt < 2; mt++) {
        int dd = wm + mt * 16 + quad * 4;              // 4 consecutive d
        #pragma unroll
        for (int nt = 0; nt < 4; nt++) {
            int qi = wn + nt * 16 + c;
            float il = invl[qi];
            float4 o = { acc[mt][nt][0] * il, acc[mt][nt][1] * il,
                         acc[mt][nt][2] * il, acc[mt][nt][3] * il };
            *(float4*)(zout + (size_t)(b * 2048 + q0 + qi) * 512 + d0 + dd) = o;
        }
    }
}

// ---------------------------------------------------------------------------
// Kernel 5 (fallback): standalone prior. Grid 8192.
// ---------------------------------------------------------------------------
__global__ __launch_bounds__(256) void k_prior(
    const float* __restrict__ x, const float* __restrict__ wsv,
    float* __restrict__ pout)
{
    __shared__ float red[4];
    __shared__ float red2[4];
    prior_body(x, wsv, pout, blockIdx.x, threadIdx.x, red, red2);
}

// ---------------------------------------------------------------------------
extern "C" void kernel_launch(void* const* d_in, const int* in_sizes, int n_in,
                              void* d_out, int out_size, void* d_ws, size_t ws_size,
                              hipStream_t stream)
{
    const float* x  = (const float*)d_in[0];
    const float* wq = (const float*)d_in[1];
    const float* wk = (const float*)d_in[2];
    const float* wv = (const float*)d_in[3];
    const float* ws = (const float*)d_in[4];

    float* zout = (float*)d_out;                       // (4,2048,512)
    float* pout = zout + (size_t)4 * 2048 * 512;       // (4,2048,2048)

    const size_t need = ((size_t)4194304 + 786432 + 3 * 4194304 + 16777216) * 2
                        + 8192 * 4;

    if (ws_size >= need) {
        unsigned short* base = (unsigned short*)d_ws;
        unsigned short* xbf  = base;
        unsigned short* wt   = xbf  + (size_t)4194304;
        unsigned short* qbf  = wt   + (size_t)786432;
        unsigned short* kbf  = qbf  + (size_t)4194304;
        unsigned short* vtbf = kbf  + (size_t)4194304;
        unsigned short* pbf  = vtbf + (size_t)4194304;
        float*          lg   = (float*)(pbf + (size_t)16777216);

        k_convert<<<dim3(7200), dim3(256), 0, stream>>>(x, wq, wk, wv, xbf, wt, lg);
        k_proj <<<dim3(768 + 8192), dim3(256), 0, stream>>>(xbf, wt, qbf, kbf, vtbf,
                                                            x, ws, pout);
        k_score<<<dim3(16, 16, 4),  dim3(256), 0, stream>>>(qbf, kbf, pbf, lg);
        k_out  <<<dim3(8, 16, 4),   dim3(256), 0, stream>>>(pbf, vtbf, lg, zout);
    } else {
        unsigned short* base = (unsigned short*)pout;
        unsigned short* pbf  = base;
        unsigned short* qbf  = base + (size_t)16777216;
        unsigned short* kbf  = qbf  + (size_t)4194304;
        unsigned short* vtbf = kbf  + (size_t)4194304;
        float*          lg   = (float*)(vtbf + (size_t)4194304);
        unsigned short* xbf  = base;                        // overlaps pbf (ok)
        unsigned short* wt   = base + (size_t)4194304;      // overlaps pbf (ok)

        k_convert<<<dim3(7200), dim3(256), 0, stream>>>(x, wq, wk, wv, xbf, wt, lg);
        k_proj <<<dim3(768),       dim3(256), 0, stream>>>(xbf, wt, qbf, kbf, vtbf,
                                                           x, ws, pout);
        k_score<<<dim3(16, 16, 4), dim3(256), 0, stream>>>(qbf, kbf, pbf, lg);
        k_out  <<<dim3(8, 16, 4),  dim3(256), 0, stream>>>(pbf, vtbf, lg, zout);
        k_prior<<<dim3(8192),      dim3(256), 0, stream>>>(x, ws, pout);
    }
}

// Round 7
// 213.308 us; speedup vs baseline: 1.0142x; 1.0142x over previous
//
#include <hip/hip_runtime.h>

typedef float f32x4 __attribute__((ext_vector_type(4)));
typedef short s16x8 __attribute__((ext_vector_type(8)));
typedef unsigned short us4 __attribute__((ext_vector_type(4)));

#define MFMA16(a, b, c) __builtin_amdgcn_mfma_f32_16x16x32_bf16(a, b, c, 0, 0, 0)

// async global->LDS DMA, 16B per lane. LDS dest must be wave-uniform base + lane*16.
#define GLOAD_LDS16(gp, lp) __builtin_amdgcn_global_load_lds( \
    (__attribute__((address_space(1))) void*)(gp),            \
    (__attribute__((address_space(3))) void*)(lp), 16, 0, 0)

__device__ __forceinline__ unsigned short f2bf(float f) {
    union { float f; unsigned u; } v; v.f = f;
    unsigned r = v.u + 0x7fffu + ((v.u >> 16) & 1u);   // RNE truncate to bf16
    return (unsigned short)(r >> 16);
}

// ---------------------------------------------------------------------------
// BK=64 GEMM core, 128x128 tile (4 waves). XOR-swizzled LDS (verified: bank
// conflicts ~0). Used by k_proj.
// ---------------------------------------------------------------------------
__device__ __forceinline__ void gemm_core128_bk64(
    const unsigned short* __restrict__ Ab, size_t Astride,
    const unsigned short* __restrict__ Bb, size_t Bstride,
    int K, unsigned short* As, unsigned short* Bs,
    int t, f32x4 acc[4][4])
{
    const int wave = t >> 6, lane = t & 63;
    const int c = lane & 15, quad = lane >> 4;
    const int wm = (wave >> 1) * 64, wn = (wave & 1) * 64;

    for (int k0 = 0; k0 < K; k0 += 64) {
        __syncthreads();
        #pragma unroll
        for (int i = 0; i < 4; i++) {
            int idx = i * 256 + t;
            int row = idx >> 3;
            int sch = (idx & 7) ^ (row & 7);
            GLOAD_LDS16(Ab + (size_t)row * Astride + k0 + sch * 8, As + idx * 8);
            GLOAD_LDS16(Bb + (size_t)row * Bstride + k0 + sch * 8, Bs + idx * 8);
        }
        __syncthreads();

        #pragma unroll
        for (int s = 0; s < 2; s++) {
            s16x8 af[4], bfr[4];
            #pragma unroll
            for (int i = 0; i < 4; i++) {
                int r = wm + i * 16 + c;
                af[i] = *(const s16x8*)(As + r * 64 + (((s << 2) | quad) ^ (r & 7)) * 8);
            }
            #pragma unroll
            for (int i = 0; i < 4; i++) {
                int r = wn + i * 16 + c;
                bfr[i] = *(const s16x8*)(Bs + r * 64 + (((s << 2) | quad) ^ (r & 7)) * 8);
            }
            #pragma unroll
            for (int mt = 0; mt < 4; mt++)
                #pragma unroll
                for (int nt = 0; nt < 4; nt++)
                    acc[mt][nt] = MFMA16(af[mt], bfr[nt], acc[mt][nt]);
        }
    }
}

// ---------------------------------------------------------------------------
// Kernel 1: convert x -> bf16 row-major; W{q,k,v} -> bf16 transposed [n][k];
// zero the l accumulator.
// ---------------------------------------------------------------------------
__global__ __launch_bounds__(256) void k_convert(
    const float* __restrict__ x, const float* __restrict__ wq,
    const float* __restrict__ wk, const float* __restrict__ wv,
    unsigned short* __restrict__ xbf, unsigned short* __restrict__ wt,
    float* __restrict__ lg)
{
    int bid = blockIdx.x, t = threadIdx.x;
    if (bid < 4096) {
        int gid = bid * 256 + t;
        float4 v = ((const float4*)x)[gid];
        us4 o = { f2bf(v.x), f2bf(v.y), f2bf(v.z), f2bf(v.w) };
        ((us4*)xbf)[gid] = o;
    } else if (bid < 7168) {
        int idx = (bid - 4096) * 256 + t;
        int w = idx >> 18;
        int r = idx & 262143;
        int k = r >> 9, n = r & 511;
        const float* src = (w == 0) ? wq : (w == 1) ? wk : wv;
        wt[((size_t)(w * 512 + n) << 9) + k] = f2bf(src[r]);
    } else {
        lg[(bid - 7168) * 256 + t] = 0.f;
    }
}

// ---------------------------------------------------------------------------
// prior body: one block per (b,i) row. sigma = x_row.Ws; row-normalized
// gaussian (inv_norm prefactor cancels). float4 stores.
// ---------------------------------------------------------------------------
__device__ __forceinline__ void prior_body(
    const float* __restrict__ x, const float* __restrict__ wsv,
    float* __restrict__ pout, int blk, int t, float* red, float* red2)
{
    int i = blk & 2047;
    const float* xr = x + (size_t)blk * 512;

    float part = xr[t] * wsv[t] + xr[t + 256] * wsv[t + 256];
    #pragma unroll
    for (int o = 32; o; o >>= 1) part += __shfl_xor(part, o, 64);
    if ((t & 63) == 0) red[t >> 6] = part;
    __syncthreads();
    float sigma = red[0] + red[1] + red[2] + red[3];

    float inv2 = 0.5f / (sigma * sigma);
    float g[8];
    float sum = 0.f;
    int j0 = t * 8;
    #pragma unroll
    for (int u = 0; u < 8; u++) {
        int j = j0 + u;
        float d = (float)(j - i);
        g[u] = (j == i) ? 1.0f : __expf(-(d * d) * inv2);
        sum += g[u];
    }
    #pragma unroll
    for (int o = 32; o; o >>= 1) sum += __shfl_xor(sum, o, 64);
    if ((t & 63) == 0) red2[t >> 6] = sum;
    __syncthreads();
    float inv = 1.0f / (red2[0] + red2[1] + red2[2] + red2[3]);

    float* pr = pout + (size_t)blk * 2048 + j0;
    float4 o0 = { g[0] * inv, g[1] * inv, g[2] * inv, g[3] * inv };
    float4 o1 = { g[4] * inv, g[5] * inv, g[6] * inv, g[7] * inv };
    ((float4*)pr)[0] = o0;
    ((float4*)pr)[1] = o1;
}

// ---------------------------------------------------------------------------
// Kernel 2: QKV projection (+ merged prior blocks in ws path). 1D grid:
// bid < 768 proj tile; bid >= 768 prior row. (Unchanged from round 6.)
// ---------------------------------------------------------------------------
__global__ __launch_bounds__(256) void k_proj(
    const unsigned short* __restrict__ xbf, const unsigned short* __restrict__ wt,
    unsigned short* __restrict__ qbf, unsigned short* __restrict__ kbf,
    unsigned short* __restrict__ vtbf,
    const float* __restrict__ x, const float* __restrict__ wsv,
    float* __restrict__ pout)
{
    __shared__ __align__(16) unsigned short As[128 * 64];
    __shared__ __align__(16) unsigned short Bs[128 * 64];
    __shared__ float red[4];
    __shared__ float red2[4];

    int bid = blockIdx.x, t = threadIdx.x;
    if (bid >= 768) {
        prior_body(x, wsv, pout, bid - 768, t, red, red2);
        return;
    }

    int bx = bid & 63, by = bid >> 6;
    int wave = t >> 6, lane = t & 63, c = lane & 15, quad = lane >> 4;
    int wm = (wave >> 1) * 64, wn = (wave & 1) * 64;
    f32x4 acc[4][4] = {};

    if (by < 8) {
        int m0 = by * 128;                         // outdim in [0,1024) = [Q|K]
        int tok0 = bx * 128;
        gemm_core128_bk64(wt + (size_t)m0 * 512, 512, xbf + (size_t)tok0 * 512, 512,
                          512, As, Bs, t, acc);

        unsigned short* dst = (m0 < 512) ? qbf : kbf;   // block-uniform
        int mbase = m0 & 511;
        #pragma unroll
        for (int mt = 0; mt < 4; mt++) {
            int dim0 = mbase + wm + mt * 16 + quad * 4;
            #pragma unroll
            for (int nt = 0; nt < 4; nt++) {
                int token = tok0 + wn + nt * 16 + c;
                us4 pk = { f2bf(acc[mt][nt][0]), f2bf(acc[mt][nt][1]),
                           f2bf(acc[mt][nt][2]), f2bf(acc[mt][nt][3]) };
                *(us4*)(dst + (size_t)token * 512 + dim0) = pk;
            }
        }
    } else {
        int m0 = bx * 128;                         // token
        int n0 = 1024 + (by - 8) * 128;            // V outdim rows in wt
        gemm_core128_bk64(xbf + (size_t)m0 * 512, 512, wt + (size_t)n0 * 512, 512,
                          512, As, Bs, t, acc);

        #pragma unroll
        for (int mt = 0; mt < 4; mt++) {
            int rw0 = m0 + wm + mt * 16 + quad * 4;      // 4 consecutive tokens
            int bb = rw0 >> 11, nn = rw0 & 2047;
            #pragma unroll
            for (int nt = 0; nt < 4; nt++) {
                int d = (n0 - 1024) + wn + nt * 16 + c;
                us4 pk = { f2bf(acc[mt][nt][0]), f2bf(acc[mt][nt][1]),
                           f2bf(acc[mt][nt][2]), f2bf(acc[mt][nt][3]) };
                *(us4*)(vtbf + ((size_t)(bb * 512 + d)) * 2048 + nn) = pk;
            }
        }
    }
}

// ---------------------------------------------------------------------------
// Kernel 3: scores, 512 threads, 256(keys) x 128(q) tile. 8 waves = 4x2
// quadrants of 64x64. Computes S^T (A=K key rows, B=Q query rows); lane holds
// 4 consecutive keys of one q-row -> us4 stores to row-major P[q][key].
// Grid (8,16,4) = 512 blocks -> 2 blocks x 8 waves = 16 waves/CU.
// ---------------------------------------------------------------------------
__global__ __launch_bounds__(512, 4) void k_score(
    const unsigned short* __restrict__ qbf, const unsigned short* __restrict__ kbf,
    unsigned short* __restrict__ pbf, float* __restrict__ lg)
{
    __shared__ __align__(16) unsigned short As[256 * 64];   // K tile, 32 KB
    __shared__ __align__(16) unsigned short Bs[128 * 64];   // Q tile, 16 KB

    int t = threadIdx.x;
    int b = blockIdx.z;
    int kt0 = blockIdx.x * 256, q0 = blockIdx.y * 128;

    const unsigned short* Ab = kbf + (size_t)(b * 2048 + kt0) * 512;
    const unsigned short* Bb = qbf + (size_t)(b * 2048 + q0) * 512;

    const int wave = t >> 6, lane = t & 63;
    const int c = lane & 15, quad = lane >> 4;
    const int wm = (wave >> 1) * 64;               // key quadrant 0..3
    const int wn = (wave & 1) * 64;                // q quadrant 0..1

    f32x4 acc[4][4] = {};

    for (int k0 = 0; k0 < 512; k0 += 64) {
        __syncthreads();
        #pragma unroll
        for (int i = 0; i < 4; i++) {              // As: 2048 slots
            int idx = i * 512 + t;
            int row = idx >> 3;
            int sch = (idx & 7) ^ (row & 7);
            GLOAD_LDS16(Ab + (size_t)row * 512 + k0 + sch * 8, As + idx * 8);
        }
        #pragma unroll
        for (int i = 0; i < 2; i++) {              // Bs: 1024 slots
            int idx = i * 512 + t;
            int row = idx >> 3;
            int sch = (idx & 7) ^ (row & 7);
            GLOAD_LDS16(Bb + (size_t)row * 512 + k0 + sch * 8, Bs + idx * 8);
        }
        __syncthreads();

        #pragma unroll
        for (int s = 0; s < 2; s++) {
            s16x8 af[4], bfr[4];
            #pragma unroll
            for (int i = 0; i < 4; i++) {
                int r = wm + i * 16 + c;
                af[i] = *(const s16x8*)(As + r * 64 + (((s << 2) | quad) ^ (r & 7)) * 8);
            }
            #pragma unroll
            for (int i = 0; i < 4; i++) {
                int r = wn + i * 16 + c;
                bfr[i] = *(const s16x8*)(Bs + r * 64 + (((s << 2) | quad) ^ (r & 7)) * 8);
            }
            #pragma unroll
            for (int mt = 0; mt < 4; mt++)
                #pragma unroll
                for (int nt = 0; nt < 4; nt++)
                    acc[mt][nt] = MFMA16(af[mt], bfr[nt], acc[mt][nt]);
        }
    }

    const float scale = 0.044194173824159216f;     // 1/sqrt(512)
    #pragma unroll
    for (int nt = 0; nt < 4; nt++) {
        int q = q0 + wn + nt * 16 + c;
        float rs = 0.f;
        unsigned short* pr = pbf + (size_t)(b * 2048 + q) * 2048 + kt0 + wm + quad * 4;
        #pragma unroll
        for (int mt = 0; mt < 4; mt++) {
            us4 pk;
            #pragma unroll
            for (int r = 0; r < 4; r++) {
                float p = __expf(acc[mt][nt][r] * scale);
                rs += p;
                pk[r] = f2bf(p);
            }
            *(us4*)(pr + mt * 16) = pk;
        }
        rs += __shfl_xor(rs, 16);
        rs += __shfl_xor(rs, 32);
        if (quad == 0) atomicAdd(&lg[b * 2048 + q], rs);
    }
}

// ---------------------------------------------------------------------------
// Kernel 4: output, BK=128: O^T tile = Vt(A, 64 d-rows) @ P(B, 128 q-rows)^T,
// K=2048 in 16 iters. Per iter: 12 GLOADs/thread in flight, 64 MFMA/wave.
// LDS rows are 128 elements = 16 chunks of 16B; XOR swizzle ch ^ (row&15)
// (16 lanes -> 8 bank-quads = 2-way alias = free). Grid (8,16,4) = 512.
// ---------------------------------------------------------------------------
__global__ __launch_bounds__(256, 3) void k_out(
    const unsigned short* __restrict__ pbf, const unsigned short* __restrict__ vtbf,
    const float* __restrict__ lg, float* __restrict__ zout)
{
    __shared__ __align__(16) unsigned short As[64 * 128];    // Vt tile 16 KB
    __shared__ __align__(16) unsigned short Bs[128 * 128];   // P tile 32 KB
    __shared__ float invl[128];

    int t = threadIdx.x;
    int b = blockIdx.z;
    int d0 = blockIdx.x * 64, q0 = blockIdx.y * 128;

    if (t < 128) invl[t] = 1.0f / lg[b * 2048 + q0 + t];

    const unsigned short* Ab = vtbf + (size_t)(b * 512 + d0) * 2048;
    const unsigned short* Bb = pbf + (size_t)(b * 2048 + q0) * 2048;

    const int wave = t >> 6, lane = t & 63;
    const int c = lane & 15, quad = lane >> 4;
    const int wm = (wave >> 1) * 32, wn = (wave & 1) * 64;

    f32x4 acc[2][4] = {};

    for (int k0 = 0; k0 < 2048; k0 += 128) {
        __syncthreads();
        #pragma unroll
        for (int i = 0; i < 4; i++) {              // As: 1024 slots (64 rows x 16)
            int idx = i * 256 + t;
            int row = idx >> 4;
            int sch = (idx & 15) ^ (row & 15);
            GLOAD_LDS16(Ab + (size_t)row * 2048 + k0 + sch * 8, As + idx * 8);
        }
        #pragma unroll
        for (int i = 0; i < 8; i++) {              // Bs: 2048 slots (128 rows x 16)
            int idx = i * 256 + t;
            int row = idx >> 4;
            int sch = (idx & 15) ^ (row & 15);
            GLOAD_LDS16(Bb + (size_t)row * 2048 + k0 + sch * 8, Bs + idx * 8);
        }
        __syncthreads();

        #pragma unroll
        for (int s = 0; s < 4; s++) {
            s16x8 af[2], bfr[4];
            #pragma unroll
            for (int i = 0; i < 2; i++) {
                int r = wm + i * 16 + c;
                af[i] = *(const s16x8*)(As + r * 128 + (((s << 2) | quad) ^ (r & 15)) * 8);
            }
            #pragma unroll
            for (int i = 0; i < 4; i++) {
                int r = wn + i * 16 + c;
                bfr[i] = *(const s16x8*)(Bs + r * 128 + (((s << 2) | quad) ^ (r & 15)) * 8);
            }
            #pragma unroll
            for (int mt = 0; mt < 2; mt++)
                #pragma unroll
                for (int nt = 0; nt < 4; nt++)
                    acc[mt][nt] = MFMA16(af[mt], bfr[nt], acc[mt][nt]);
        }
    }

    #pragma unroll
    for (int mt = 0; mt < 2; mt++) {
        int dd = wm + mt * 16 + quad * 4;              // 4 consecutive d
        #pragma unroll
        for (int nt = 0; nt < 4; nt++) {
            int qi = wn + nt * 16 + c;
            float il = invl[qi];
            float4 o = { acc[mt][nt][0] * il, acc[mt][nt][1] * il,
                         acc[mt][nt][2] * il, acc[mt][nt][3] * il };
            *(float4*)(zout + (size_t)(b * 2048 + q0 + qi) * 512 + d0 + dd) = o;
        }
    }
}

// ---------------------------------------------------------------------------
// Kernel 5 (fallback): standalone prior. Grid 8192.
// ---------------------------------------------------------------------------
__global__ __launch_bounds__(256) void k_prior(
    const float* __restrict__ x, const float* __restrict__ wsv,
    float* __restrict__ pout)
{
    __shared__ float red[4];
    __shared__ float red2[4];
    prior_body(x, wsv, pout, blockIdx.x, threadIdx.x, red, red2);
}

// ---------------------------------------------------------------------------
extern "C" void kernel_launch(void* const* d_in, const int* in_sizes, int n_in,
                              void* d_out, int out_size, void* d_ws, size_t ws_size,
                              hipStream_t stream)
{
    const float* x  = (const float*)d_in[0];
    const float* wq = (const float*)d_in[1];
    const float* wk = (const float*)d_in[2];
    const float* wv = (const float*)d_in[3];
    const float* ws = (const float*)d_in[4];

    float* zout = (float*)d_out;                       // (4,2048,512)
    float* pout = zout + (size_t)4 * 2048 * 512;       // (4,2048,2048)

    const size_t need = ((size_t)4194304 + 786432 + 3 * 4194304 + 16777216) * 2
                        + 8192 * 4;

    if (ws_size >= need) {
        unsigned short* base = (unsigned short*)d_ws;
        unsigned short* xbf  = base;
        unsigned short* wt   = xbf  + (size_t)4194304;
        unsigned short* qbf  = wt   + (size_t)786432;
        unsigned short* kbf  = qbf  + (size_t)4194304;
        unsigned short* vtbf = kbf  + (size_t)4194304;
        unsigned short* pbf  = vtbf + (size_t)4194304;
        float*          lg   = (float*)(pbf + (size_t)16777216);

        k_convert<<<dim3(7200), dim3(256), 0, stream>>>(x, wq, wk, wv, xbf, wt, lg);
        k_proj <<<dim3(768 + 8192), dim3(256), 0, stream>>>(xbf, wt, qbf, kbf, vtbf,
                                                            x, ws, pout);
        k_score<<<dim3(8, 16, 4),   dim3(512), 0, stream>>>(qbf, kbf, pbf, lg);
        k_out  <<<dim3(8, 16, 4),   dim3(256), 0, stream>>>(pbf, vtbf, lg, zout);
    } else {
        unsigned short* base = (unsigned short*)pout;
        unsigned short* pbf  = base;
        unsigned short* qbf  = base + (size_t)16777216;
        unsigned short* kbf  = qbf  + (size_t)4194304;
        unsigned short* vtbf = kbf  + (size_t)4194304;
        float*          lg   = (float*)(vtbf + (size_t)4194304);
        unsigned short* xbf  = base;                        // overlaps pbf (ok)
        unsigned short* wt   = base + (size_t)4194304;      // overlaps pbf (ok)

        k_convert<<<dim3(7200), dim3(256), 0, stream>>>(x, wq, wk, wv, xbf, wt, lg);
        k_proj <<<dim3(768),       dim3(256), 0, stream>>>(xbf, wt, qbf, kbf, vtbf,
                                                           x, ws, pout);
        k_score<<<dim3(8, 16, 4),  dim3(512), 0, stream>>>(qbf, kbf, pbf, lg);
        k_out  <<<dim3(8, 16, 4),  dim3(256), 0, stream>>>(pbf, vtbf, lg, zout);
        k_prior<<<dim3(8192),      dim3(256), 0, stream>>>(x, ws, pout);
    }
}